// Round 11
// baseline (174.548 us; speedup 1.0000x reference)
//
#include <hip/hip_runtime.h>

typedef float vf2  __attribute__((ext_vector_type(2)));

#define ROWS 66   // transpose-buffer row stride in float2 (64 + 2 pad -> bank stagger)
#define FENCE() asm volatile("" ::: "memory")

// merged-diagonal angle for wire j of diagonal d (wave-uniform); d, j compile-time
#define ALPHA(d, j) (((d) & 1) \
  ? (W[((((d)>>1)*2+1)*12+(j))*3+0] + W[((((d)>>1)*2+0)*12+(j))*3+2]) \
  : (W[((((d)>>1)*2+0)*12+(j))*3+0] + xr[(j)] + W[(((((d)>>1)-1)*2+1)*12+(j))*3+2]))

// Hoist the 6 (c,t) pairs of one GATES6 pass as 3 ds_read_b128 into registers.
#define LOADCT(dst, sl, par) do{ \
  const float4* p_ = (const float4*)&scsl[(sl)*12 + ((par)?0:6)]; \
  float4 a_ = p_[0], b_ = p_[1], c_ = p_[2]; \
  dst[0].x=a_.x; dst[0].y=a_.y; dst[1].x=a_.z; dst[1].y=a_.w; \
  dst[2].x=b_.x; dst[2].y=b_.y; dst[3].x=b_.z; dst[3].y=b_.w; \
  dst[4].x=c_.x; dst[4].y=c_.y; dst[5].x=c_.z; dst[5].y=c_.w; \
}while(0)

// 6 RY gates, tan-form + packed FMA, (c,t) pairs pre-hoisted in ct[] registers.
// r0 = a - t*b ; r1 = b + t*a  (R9/R10-verified asm)
#define GATES6R(ct) do{ \
  _Pragma("unroll") \
  for (int lb = 0; lb < 6; lb++){ \
    vf2 ct_ = ct[5-lb]; \
    _Pragma("unroll") \
    for (int w0 = 0; w0 < 64; w0++){ \
      if (w0 & (1 << lb)) continue; \
      const int w1 = w0 | (1 << lb); \
      vf2 a_ = st[w0], b_ = st[w1], r0_, r1_; \
      asm("v_pk_fma_f32 %0, %1, %2, %3 op_sel:[1,0,0] op_sel_hi:[1,1,1] neg_lo:[1,0,0] neg_hi:[1,0,0]" \
          : "=v"(r0_) : "v"(ct_), "v"(b_), "v"(a_)); \
      asm("v_pk_fma_f32 %0, %1, %2, %3 op_sel:[1,0,0] op_sel_hi:[1,1,1]" \
          : "=v"(r1_) : "v"(ct_), "v"(a_), "v"(b_)); \
      st[w0] = r0_; st[w1] = r1_; \
    } \
  } \
}while(0)

// swap lane-domain <-> reg-domain through LDS (R5/R8/R10-verified single-phase)
#define TRANSPOSE() do{ \
  _Pragma("unroll") \
  for (int w = 0; w < 64; w++){ \
    xbuf[w * ROWS + u] = st[w]; \
  } \
  FENCE(); \
  _Pragma("unroll") \
  for (int j = 0; j < 32; j++){ \
    float4 f_ = ((const float4*)&xbuf[u * ROWS])[j]; \
    vf2 e0_, e1_; e0_.x = f_.x; e0_.y = f_.y; e1_.x = f_.z; e1_.y = f_.w; \
    st[2*j] = e0_; st[2*j+1] = e1_; \
  } \
  FENCE(); \
}while(0)

// merged diagonal d (runtime), PACKED (R9-verified body):
//  - reg part: dual-form table (A=dph, B=i*dph) in one float4 -> 1 ds_read_b128/w
//    (broadcast, conflict-free), complex mul = pk_mul + pk_fma with op_sel
//  - lane part: 16 sign-variant registers lv[cls], cls compile-time from w bits
//    {5,4,1,0}; sign folded via XOR on bit 31 at build
//  Inner loop: 4 VALU + 1 LDS per amplitude (vs ~13 scalar in R8/R10 form).
#define DIAG(d, par) do{ \
  vf2 lp_ = (d)==1 ? lA[0] : (d)==2 ? lA[1] : (d)==3 ? lA[2] : (d)==4 ? lA[3] : lA[4]; \
  const unsigned m_ = (par) ? ( ((u >> 5) & 1u) | ((u & 1u) << 5) ) \
                            : ( (((u >> 1) & 1u) << 5) | ((u & 1u) << 4) \
                              | (((u >> 5) & 1u) << 1) | ((u >> 4) & 1u) ); \
  vf2 lv[16]; \
  _Pragma("unroll") \
  for (int c = 0; c < 16; c++){ \
    const unsigned cb = (((c >> 3) & 1u) << 5) | (((c >> 2) & 1u) << 4) \
                      | (((c >> 1) & 1u) << 1) | (c & 1u); \
    const unsigned msk = (unsigned)__popc(m_ & cb) << 31;   /* parity bit -> sign bit */ \
    vf2 t_; \
    t_.x = __uint_as_float(__float_as_uint(lp_.x) ^ msk); \
    t_.y = __uint_as_float(__float_as_uint(lp_.y) ^ msk); \
    lv[c] = t_; \
  } \
  _Pragma("unroll") \
  for (int w = 0; w < 64; w++){ \
    float4 dq_ = tabsAB[(d)-1][w]; \
    vf2 dA_; dA_.x = dq_.x; dA_.y = dq_.y; \
    vf2 dB_; dB_.x = dq_.z; dB_.y = dq_.w; \
    const int cls_ = (((w >> 5) & 1) << 3) | (((w >> 4) & 1) << 2) \
                   | (((w >> 1) & 1) << 1) | (w & 1); \
    vf2 a_ = st[w], p1_, r_, p2_, r2_; \
    asm("v_pk_mul_f32 %0, %1, %2 op_sel:[0,0] op_sel_hi:[0,1]" \
        : "=v"(p1_) : "v"(a_), "v"(dA_)); \
    asm("v_pk_fma_f32 %0, %1, %2, %3 op_sel:[1,0,0] op_sel_hi:[1,1,1]" \
        : "=v"(r_) : "v"(a_), "v"(dB_), "v"(p1_)); \
    vf2 lvc_ = lv[cls_]; \
    asm("v_pk_mul_f32 %0, %1, %2 op_sel:[0,0] op_sel_hi:[0,1]" \
        : "=v"(p2_) : "v"(r_), "v"(lvc_)); \
    asm("v_pk_fma_f32 %0, %1, %2, %3 op_sel:[1,1,0] op_sel_hi:[1,0,1] neg_lo:[1,0,0] neg_hi:[0,0,0]" \
        : "=v"(r2_) : "v"(r_), "v"(lvc_), "v"(p2_)); \
    st[w] = r2_; \
  } \
}while(0)

__global__ __attribute__((amdgpu_flat_work_group_size(64,64)))
__attribute__((amdgpu_waves_per_eu(1)))
void qiddm_wave(const float* __restrict__ gx,
                const float* __restrict__ gcw,
                const float* __restrict__ gcb,
                const float* __restrict__ gw1,
                const float* __restrict__ glw,
                const float* __restrict__ glb,
                float* __restrict__ gout)
{
  // One wave per sample; state as vf2 st[64] (SROA -> 64 aligned VGPR pairs).
  // L0 layout: lane u = idx bits 11..6 (wires 0..5), reg w = idx bits 5..0 (wires 6..11)
  // L1 layout: lane u = idx bits 5..0,  reg w = idx bits 11..6
  // R11 = R10 structure (compile-time parity, hoisted (c,t)) + R9 packed DIAG:
  // R9 proved the packed DIAG removes ~17us-eq VALU (46->32.5% busy) but the old
  // stall-bound structure hid it; R10 removed the stalls (124->120).  Combining.
  // ltab stays in lA registers so LDS = 33792+5120+576 = 39488 (same 4-blocks/CU
  // bucket; LDS-resident ltab would tip to 3 blocks/CU).
  __shared__ vf2 xbuf[64 * ROWS];     // 33792 B transpose buffer (aliases conv image)
  __shared__ float4 tabsAB[5][64];    // reg-domain diagonal, dual form (A=dph, B=i*dph)
  __shared__ vf2 scsl[72];            // (cos, tan) of theta/2 per (sublayer, wire)

  const int u = threadIdx.x;        // lane 0..63
  const int bid = blockIdx.x;

  float xr[12];                     // circuit inputs / expvals (constant-indexed only)

  // ---------- conv 3x3 s2 p1 + bias + GAP ----------
  {
    float* img = (float*)xbuf;
#pragma unroll
    for (int i = 0; i < 4; i++){
      float4 q4 = ((const float4*)gx)[(size_t)bid * 256 + i * 64 + u];
      ((float4*)img)[i * 64 + u] = q4;
    }
    FENCE();
    float p[4][9];
#pragma unroll
    for (int i = 0; i < 4; i++){
      int pos = u + 64 * i, oi = pos >> 4, oj = pos & 15;
#pragma unroll
      for (int ki = 0; ki < 3; ki++)
#pragma unroll
        for (int kj = 0; kj < 3; kj++){
          int ri = 2*oi - 1 + ki, cj = 2*oj - 1 + kj;
          p[i][ki*3+kj] = (ri >= 0 && ri < 32 && cj >= 0 && cj < 32) ? img[ri*32+cj] : 0.0f;
        }
    }
#pragma unroll
    for (int q = 0; q < 12; q++){
      float a = 0.0f;
#pragma unroll
      for (int e = 0; e < 9; e++){
        float wv = gcw[q*9+e];                  // uniform -> scalarized
#pragma unroll
        for (int i = 0; i < 4; i++) a += p[i][e] * wv;
      }
#pragma unroll
      for (int off = 32; off; off >>= 1) a += __shfl_xor(a, off);
      xr[q] = gcb[q] + a * (1.0f/256.0f);
    }
  }

#pragma unroll 1
  for (int n = 0; n < 2; n++){
    const float* W = gw1 + n * 216;

    // ---- RY (cos, tan) table (72 gates) + deferred-cosine product C = prod c[12..71]
    float myc = 1.0f;
#pragma unroll
    for (int rep = 0; rep < 2; rep++){
      int e = u + rep * 64;
      if (e < 72){
        float sv, cv; __sincosf(0.5f * W[e*3+1], &sv, &cv);
        vf2 ct; ct.x = cv; ct.y = __fdividef(sv, cv); scsl[e] = ct;
        if (e >= 12) myc *= cv;
      }
    }
#pragma unroll
    for (int off = 32; off; off >>= 1) myc *= __shfl_xor(myc, off);
    const float C2 = myc * myc;                 // wave-uniform probability scale

    // ---- diagonal tables: reg-domain -> tabsAB (dual form), lane-domain -> lA regs ----
    vf2 lA[5];                                  // compile-time indexed here; select-chain in DIAG
#pragma unroll
    for (int d = 1; d <= 5; d++){
      const int par = d & 1;                    // 1 -> applied in L1 (r=1), 0 -> L0 (r=2)
      const int r = par ? 1 : 2;
      {
        float ph = 0.0f;
#pragma unroll
        for (int lb = 0; lb < 6; lb++){
          int wire = par ? (5 - lb) : (11 - lb);          // reg-domain wires
          ph += ALPHA(d, wire) * ((float)((u >> lb) & 1) - 0.5f);
        }
        int idx_r = par ? (u << 6) : u;
        int y = ((idx_r << r) | (idx_r >> (12 - r))) & 0xFFF;
        int s = __popc(idx_r & y) & 1;                    // within-reg CZ parity
        float sv, cv; __sincosf(ph, &sv, &cv);
        if (s){ sv = -sv; cv = -cv; }
        float4 q_; q_.x = cv; q_.y = sv; q_.z = -sv; q_.w = cv;   // A = dph, B = i*dph
        tabsAB[d-1][u] = q_;
      }
      {
        float ph = 0.0f;
#pragma unroll
        for (int lb = 0; lb < 6; lb++){
          int wire = par ? (11 - lb) : (5 - lb);          // lane-domain wires
          ph += ALPHA(d, wire) * ((float)((u >> lb) & 1) - 0.5f);
        }
        int idx_l = par ? u : (u << 6);
        int y = ((idx_l << r) | (idx_l >> (12 - r))) & 0xFFF;
        int s = __popc(idx_l & y) & 1;                    // within-lane CZ parity
        float sv, cv; __sincosf(ph, &sv, &cv);
        vf2 e_; e_.x = cv; e_.y = sv; if (s) e_ = -e_;
        lA[d-1] = e_;                                     // registers, not LDS
      }
    }
    FENCE();                                    // table writes before circuit reads

    // ---- direct product-state init in L1 (sublayer 0 closed-form; s_j = c_j*t_j)
    vf2 st[64];
    float fl = 1.0f;
#pragma unroll
    for (int lb = 0; lb < 6; lb++){
      vf2 ct = scsl[11 - lb];
      fl *= ((u >> lb) & 1) ? (ct.x * ct.y) : ct.x;   // runtime select, constant index
    }
    float qc[6], qs[6];
#pragma unroll
    for (int rb = 0; rb < 6; rb++){
      vf2 ct = scsl[5 - rb]; qc[rb] = ct.x; qs[rb] = ct.x * ct.y;
    }
#pragma unroll
    for (int w = 0; w < 64; w++){               // w compile-time -> selects fold, CSE shares
      float Qw =  ((w & 1)  ? qs[0] : qc[0]);
      Qw      *=  ((w & 2)  ? qs[1] : qc[1]);
      Qw      *=  ((w & 4)  ? qs[2] : qc[2]);
      Qw      *=  ((w & 8)  ? qs[3] : qc[3]);
      Qw      *=  ((w & 16) ? qs[4] : qc[4]);
      Qw      *=  ((w & 32) ? qs[5] : qc[5]);
      vf2 e_; e_.x = fl * Qw; e_.y = 0.0f;
      st[w] = e_;
    }

    // ---- circuit: 5 sublayers (k=2..11 regrouped), compile-time parity per block ----
    // odd sl (1,3,5):  DIAG(sl,1); G6(par=1); TRANSPOSE; G6(par=0)
    // even sl (2,4):   DIAG(sl,0); G6(par=0); TRANSPOSE; G6(par=1)
#pragma unroll 1
    for (int slp = 0; slp < 3; slp++){
      const int sl = 2*slp + 1;                 // odd sublayer
      {
        vf2 ctA[6], ctB[6];
        LOADCT(ctA, sl, 1);
        DIAG(sl, 1);
        GATES6R(ctA);
        LOADCT(ctB, sl, 0);                     // latency hides under transpose traffic
        TRANSPOSE();
        GATES6R(ctB);
      }
      if (slp < 2){                             // even sublayer (uniform branch)
        const int sle = sl + 1;
        vf2 ctA[6], ctB[6];
        LOADCT(ctA, sle, 0);
        DIAG(sle, 0);
        GATES6R(ctA);
        LOADCT(ctB, sle, 1);
        TRANSPOSE();
        GATES6R(ctB);
      }
    }

    // ---- measurement in L0; computed state = true/C, so p_true = p~ * C2 ----
    // half-sum form: mm[i] = P - 2*S_i, S_i = sum of pr over w with bit (5-i) set
    {
      float P = 0.f, S[6] = {0.f,0.f,0.f,0.f,0.f,0.f};   // wires 6..11 (reg bits 5..0)
#pragma unroll
      for (int w = 0; w < 64; w++){
        float re = st[w].x, im = st[w].y;
        float pr = __builtin_fmaf(im, im, re*re);
        P += pr;
#pragma unroll
        for (int i = 0; i < 6; i++)
          if ((w >> (5 - i)) & 1) S[i] += pr;   // compile-time predicate -> 32 adds per i
      }
#pragma unroll
      for (int q = 0; q < 12; q++){
        float val = (q < 6) ? (((u >> (5 - q)) & 1) ? -P : P)   // wires 0..5 (lane bits)
                            : (P - 2.0f * S[q - 6]);
#pragma unroll
        for (int off = 32; off; off >>= 1) val += __shfl_xor(val, off);
        xr[q] = val * C2;                       // undo deferred cosines (uniform)
      }
    }
  }

  // ---------- final linear ----------
  {
#pragma unroll
    for (int i = 0; i < 16; i++){
      int o = i * 64 + u;
      const float4* wr = (const float4*)(glw + o * 12);   // 48B rows, 16B aligned
      float4 w0 = wr[0], w1 = wr[1], w2 = wr[2];
      float a = glb[o];
      a += xr[0]*w0.x + xr[1]*w0.y + xr[2]*w0.z + xr[3]*w0.w;
      a += xr[4]*w1.x + xr[5]*w1.y + xr[6]*w1.z + xr[7]*w1.w;
      a += xr[8]*w2.x + xr[9]*w2.y + xr[10]*w2.z + xr[11]*w2.w;
      gout[(size_t)bid * 1024 + o] = a;
    }
  }
}

extern "C" void kernel_launch(void* const* d_in, const int* in_sizes, int n_in,
                              void* d_out, int out_size, void* d_ws, size_t ws_size,
                              hipStream_t stream)
{
  (void)n_in; (void)d_ws; (void)ws_size; (void)out_size;
  const float* x  = (const float*)d_in[0];
  const float* cw = (const float*)d_in[1];
  const float* cb = (const float*)d_in[2];
  const float* w1 = (const float*)d_in[3];
  const float* lw = (const float*)d_in[4];
  const float* lb = (const float*)d_in[5];
  float* out = (float*)d_out;
  const int nb = in_sizes[0] / 1024;   // 2048 samples, one wave each
  hipLaunchKernelGGL(qiddm_wave, dim3(nb), dim3(64), 0, stream,
                     x, cw, cb, w1, lw, lb, out);
}

// Round 12
// 168.780 us; speedup vs baseline: 1.0342x; 1.0342x over previous
//
#include <hip/hip_runtime.h>

typedef float vf2  __attribute__((ext_vector_type(2)));

__device__ __forceinline__ vf2 cmulv(vf2 a, vf2 b){
  vf2 br; br.x = -b.y; br.y = b.x;
  return a.x*b + a.y*br;
}

#define ROWS 66   // transpose-buffer row stride in float2 (64 + 2 pad -> bank stagger)
#define FENCE() asm volatile("" ::: "memory")

// merged-diagonal angle for wire j of diagonal d (wave-uniform); d, j compile-time
#define ALPHA(d, j) (((d) & 1) \
  ? (W[((((d)>>1)*2+1)*12+(j))*3+0] + W[((((d)>>1)*2+0)*12+(j))*3+2]) \
  : (W[((((d)>>1)*2+0)*12+(j))*3+0] + xr[(j)] + W[(((((d)>>1)-1)*2+1)*12+(j))*3+2]))

// Hoist the 6 (c,t) pairs of one GATES6 pass as 3 ds_read_b128 into registers.
#define LOADCT(dst, sl, par) do{ \
  const float4* p_ = (const float4*)&scsl[(sl)*12 + ((par)?0:6)]; \
  float4 a_ = p_[0], b_ = p_[1], c_ = p_[2]; \
  dst[0].x=a_.x; dst[0].y=a_.y; dst[1].x=a_.z; dst[1].y=a_.w; \
  dst[2].x=b_.x; dst[2].y=b_.y; dst[3].x=b_.z; dst[3].y=b_.w; \
  dst[4].x=c_.x; dst[4].y=c_.y; dst[5].x=c_.z; dst[5].y=c_.w; \
}while(0)

// 6 RY gates, tan-form + packed FMA, (c,t) pairs pre-hoisted in ct[] registers.
// r0 = a - t*b ; r1 = b + t*a  (R9/R10-verified asm)
#define GATES6R(ct) do{ \
  _Pragma("unroll") \
  for (int lb = 0; lb < 6; lb++){ \
    vf2 ct_ = ct[5-lb]; \
    _Pragma("unroll") \
    for (int w0 = 0; w0 < 64; w0++){ \
      if (w0 & (1 << lb)) continue; \
      const int w1 = w0 | (1 << lb); \
      vf2 a_ = st[w0], b_ = st[w1], r0_, r1_; \
      asm("v_pk_fma_f32 %0, %1, %2, %3 op_sel:[1,0,0] op_sel_hi:[1,1,1] neg_lo:[1,0,0] neg_hi:[1,0,0]" \
          : "=v"(r0_) : "v"(ct_), "v"(b_), "v"(a_)); \
      asm("v_pk_fma_f32 %0, %1, %2, %3 op_sel:[1,0,0] op_sel_hi:[1,1,1]" \
          : "=v"(r1_) : "v"(ct_), "v"(a_), "v"(b_)); \
      st[w0] = r0_; st[w1] = r1_; \
    } \
  } \
}while(0)

// swap lane-domain <-> reg-domain through LDS (R5/R8/R10-verified single-phase)
#define TRANSPOSE() do{ \
  _Pragma("unroll") \
  for (int w = 0; w < 64; w++){ \
    xbuf[w * ROWS + u] = st[w]; \
  } \
  FENCE(); \
  _Pragma("unroll") \
  for (int j = 0; j < 32; j++){ \
    float4 f_ = ((const float4*)&xbuf[u * ROWS])[j]; \
    vf2 e0_, e1_; e0_.x = f_.x; e0_.y = f_.y; e1_.x = f_.z; e1_.y = f_.w; \
    st[2*j] = e0_; st[2*j+1] = e1_; \
  } \
  FENCE(); \
}while(0)

// merged diagonal d (runtime), par COMPILE-TIME (R10-verified scalar body), with
// tabs read as PAIRED b128 (two adjacent vf2 per ds_read_b128: 32 LDS ops not 64,
// -320 LDS instrs/wave vs R10; rows 512B-aligned so the float4 cast is clean)
#define DIAG(d, par) do{ \
  vf2 lp_ = ltab[(d)-1][u]; \
  vf2 lpn_ = -lp_; \
  const unsigned m_ = (par) ? ( ((u >> 5) & 1u) | ((u & 1u) << 5) ) \
                            : ( (((u >> 1) & 1u) << 5) | ((u & 1u) << 4) \
                              | (((u >> 5) & 1u) << 1) | ((u >> 4) & 1u) ); \
  _Pragma("unroll") \
  for (int j = 0; j < 32; j++){ \
    float4 dq_ = ((const float4*)&tabs[(d)-1][0])[j]; \
    vf2 d0_; d0_.x = dq_.x; d0_.y = dq_.y; \
    vf2 d1_; d1_.x = dq_.z; d1_.y = dq_.w; \
    { \
      const int w = 2*j; \
      const int sx_ = __popc((unsigned)w & m_) & 1; \
      vf2 a_ = st[w]; \
      vf2 t_ = cmulv(a_, d0_); \
      st[w] = cmulv(t_, sx_ ? lpn_ : lp_); \
    } \
    { \
      const int w = 2*j + 1; \
      const int sx_ = __popc((unsigned)w & m_) & 1; \
      vf2 a_ = st[w]; \
      vf2 t_ = cmulv(a_, d1_); \
      st[w] = cmulv(t_, sx_ ? lpn_ : lp_); \
    } \
  } \
}while(0)

__global__ __attribute__((amdgpu_flat_work_group_size(64,64)))
__attribute__((amdgpu_waves_per_eu(1)))
void qiddm_wave(const float* __restrict__ gx,
                const float* __restrict__ gcw,
                const float* __restrict__ gcb,
                const float* __restrict__ gw1,
                const float* __restrict__ glw,
                const float* __restrict__ glb,
                float* __restrict__ gout)
{
  // One wave per sample; state as vf2 st[64] (SROA -> 64 aligned VGPR pairs).
  // L0 layout: lane u = idx bits 11..6 (wires 0..5), reg w = idx bits 5..0 (wires 6..11)
  // L1 layout: lane u = idx bits 5..0,  reg w = idx bits 11..6
  // R12 = revert to R10 (best: 168.0 harness / 120.4 dispatch) + paired-b128 tabs
  // reads in DIAG.  R11's packed DIAG retired: VALU savings repaid in LDS stalls
  // (2x table bytes + lv[16] serial build; 36.5% busy but +4us wall).
  // Model: R10 sits at 86% of the solo-wave VALU-saturation bound (43% busy vs the
  // 50% solo ceiling on SIMD-32); remaining levers are stall shaves only.
  __shared__ vf2 xbuf[64 * ROWS];   // 33792 B transpose buffer (aliases conv image)
  __shared__ vf2 tabs[5][64];       // reg-domain diagonal tables
  __shared__ vf2 ltab[5][64];       // lane-domain diagonal factors
  __shared__ vf2 scsl[72];          // (cos, tan) of theta/2 per (sublayer, wire)

  const int u = threadIdx.x;        // lane 0..63
  const int bid = blockIdx.x;

  float xr[12];                     // circuit inputs / expvals (constant-indexed only)

  // ---------- conv 3x3 s2 p1 + bias + GAP ----------
  {
    float* img = (float*)xbuf;
#pragma unroll
    for (int i = 0; i < 4; i++){
      float4 q4 = ((const float4*)gx)[(size_t)bid * 256 + i * 64 + u];
      ((float4*)img)[i * 64 + u] = q4;
    }
    FENCE();
    float p[4][9];
#pragma unroll
    for (int i = 0; i < 4; i++){
      int pos = u + 64 * i, oi = pos >> 4, oj = pos & 15;
#pragma unroll
      for (int ki = 0; ki < 3; ki++)
#pragma unroll
        for (int kj = 0; kj < 3; kj++){
          int ri = 2*oi - 1 + ki, cj = 2*oj - 1 + kj;
          p[i][ki*3+kj] = (ri >= 0 && ri < 32 && cj >= 0 && cj < 32) ? img[ri*32+cj] : 0.0f;
        }
    }
#pragma unroll
    for (int q = 0; q < 12; q++){
      float a = 0.0f;
#pragma unroll
      for (int e = 0; e < 9; e++){
        float wv = gcw[q*9+e];                  // uniform -> scalarized
#pragma unroll
        for (int i = 0; i < 4; i++) a += p[i][e] * wv;
      }
#pragma unroll
      for (int off = 32; off; off >>= 1) a += __shfl_xor(a, off);
      xr[q] = gcb[q] + a * (1.0f/256.0f);
    }
  }

#pragma unroll 1
  for (int n = 0; n < 2; n++){
    const float* W = gw1 + n * 216;

    // ---- RY (cos, tan) table (72 gates) + deferred-cosine product C = prod c[12..71]
    float myc = 1.0f;
#pragma unroll
    for (int rep = 0; rep < 2; rep++){
      int e = u + rep * 64;
      if (e < 72){
        float sv, cv; __sincosf(0.5f * W[e*3+1], &sv, &cv);
        vf2 ct; ct.x = cv; ct.y = __fdividef(sv, cv); scsl[e] = ct;
        if (e >= 12) myc *= cv;
      }
    }
#pragma unroll
    for (int off = 32; off; off >>= 1) myc *= __shfl_xor(myc, off);
    const float C2 = myc * myc;                 // wave-uniform probability scale

    // ---- diagonal tables: reg-domain (tabs) and lane-domain (ltab), d unrolled ----
#pragma unroll
    for (int d = 1; d <= 5; d++){
      const int par = d & 1;                    // 1 -> applied in L1 (r=1), 0 -> L0 (r=2)
      const int r = par ? 1 : 2;
      {
        float ph = 0.0f;
#pragma unroll
        for (int lb = 0; lb < 6; lb++){
          int wire = par ? (5 - lb) : (11 - lb);          // reg-domain wires
          ph += ALPHA(d, wire) * ((float)((u >> lb) & 1) - 0.5f);
        }
        int idx_r = par ? (u << 6) : u;
        int y = ((idx_r << r) | (idx_r >> (12 - r))) & 0xFFF;
        int s = __popc(idx_r & y) & 1;                    // within-reg CZ parity
        float sv, cv; __sincosf(ph, &sv, &cv);
        vf2 e_; e_.x = cv; e_.y = sv; if (s) e_ = -e_;
        tabs[d-1][u] = e_;
      }
      {
        float ph = 0.0f;
#pragma unroll
        for (int lb = 0; lb < 6; lb++){
          int wire = par ? (11 - lb) : (5 - lb);          // lane-domain wires
          ph += ALPHA(d, wire) * ((float)((u >> lb) & 1) - 0.5f);
        }
        int idx_l = par ? u : (u << 6);
        int y = ((idx_l << r) | (idx_l >> (12 - r))) & 0xFFF;
        int s = __popc(idx_l & y) & 1;                    // within-lane CZ parity
        float sv, cv; __sincosf(ph, &sv, &cv);
        vf2 e_; e_.x = cv; e_.y = sv; if (s) e_ = -e_;
        ltab[d-1][u] = e_;
      }
    }
    FENCE();                                    // table writes before circuit reads

    // ---- direct product-state init in L1 (sublayer 0 closed-form; s_j = c_j*t_j)
    vf2 st[64];
    float fl = 1.0f;
#pragma unroll
    for (int lb = 0; lb < 6; lb++){
      vf2 ct = scsl[11 - lb];
      fl *= ((u >> lb) & 1) ? (ct.x * ct.y) : ct.x;   // runtime select, constant index
    }
    float qc[6], qs[6];
#pragma unroll
    for (int rb = 0; rb < 6; rb++){
      vf2 ct = scsl[5 - rb]; qc[rb] = ct.x; qs[rb] = ct.x * ct.y;
    }
#pragma unroll
    for (int w = 0; w < 64; w++){               // w compile-time -> selects fold, CSE shares
      float Qw =  ((w & 1)  ? qs[0] : qc[0]);
      Qw      *=  ((w & 2)  ? qs[1] : qc[1]);
      Qw      *=  ((w & 4)  ? qs[2] : qc[2]);
      Qw      *=  ((w & 8)  ? qs[3] : qc[3]);
      Qw      *=  ((w & 16) ? qs[4] : qc[4]);
      Qw      *=  ((w & 32) ? qs[5] : qc[5]);
      vf2 e_; e_.x = fl * Qw; e_.y = 0.0f;
      st[w] = e_;
    }

    // ---- circuit: 5 sublayers (k=2..11 regrouped), compile-time parity per block ----
    // odd sl (1,3,5):  DIAG(sl,1); G6(par=1); TRANSPOSE; G6(par=0)
    // even sl (2,4):   DIAG(sl,0); G6(par=0); TRANSPOSE; G6(par=1)
#pragma unroll 1
    for (int slp = 0; slp < 3; slp++){
      const int sl = 2*slp + 1;                 // odd sublayer
      {
        vf2 ctA[6], ctB[6];
        LOADCT(ctA, sl, 1);
        DIAG(sl, 1);
        GATES6R(ctA);
        LOADCT(ctB, sl, 0);                     // latency hides under transpose traffic
        TRANSPOSE();
        GATES6R(ctB);
      }
      if (slp < 2){                             // even sublayer (uniform branch)
        const int sle = sl + 1;
        vf2 ctA[6], ctB[6];
        LOADCT(ctA, sle, 0);
        DIAG(sle, 0);
        GATES6R(ctA);
        LOADCT(ctB, sle, 1);
        TRANSPOSE();
        GATES6R(ctB);
      }
    }

    // ---- measurement in L0; computed state = true/C, so p_true = p~ * C2 ----
    // half-sum form: mm[i] = P - 2*S_i, S_i = sum of pr over w with bit (5-i) set
    {
      float P = 0.f, S[6] = {0.f,0.f,0.f,0.f,0.f,0.f};   // wires 6..11 (reg bits 5..0)
#pragma unroll
      for (int w = 0; w < 64; w++){
        float re = st[w].x, im = st[w].y;
        float pr = __builtin_fmaf(im, im, re*re);
        P += pr;
#pragma unroll
        for (int i = 0; i < 6; i++)
          if ((w >> (5 - i)) & 1) S[i] += pr;   // compile-time predicate -> 32 adds per i
      }
#pragma unroll
      for (int q = 0; q < 12; q++){
        float val = (q < 6) ? (((u >> (5 - q)) & 1) ? -P : P)   // wires 0..5 (lane bits)
                            : (P - 2.0f * S[q - 6]);
#pragma unroll
        for (int off = 32; off; off >>= 1) val += __shfl_xor(val, off);
        xr[q] = val * C2;                       // undo deferred cosines (uniform)
      }
    }
  }

  // ---------- final linear ----------
  {
#pragma unroll
    for (int i = 0; i < 16; i++){
      int o = i * 64 + u;
      const float4* wr = (const float4*)(glw + o * 12);   // 48B rows, 16B aligned
      float4 w0 = wr[0], w1 = wr[1], w2 = wr[2];
      float a = glb[o];
      a += xr[0]*w0.x + xr[1]*w0.y + xr[2]*w0.z + xr[3]*w0.w;
      a += xr[4]*w1.x + xr[5]*w1.y + xr[6]*w1.z + xr[7]*w1.w;
      a += xr[8]*w2.x + xr[9]*w2.y + xr[10]*w2.z + xr[11]*w2.w;
      gout[(size_t)bid * 1024 + o] = a;
    }
  }
}

extern "C" void kernel_launch(void* const* d_in, const int* in_sizes, int n_in,
                              void* d_out, int out_size, void* d_ws, size_t ws_size,
                              hipStream_t stream)
{
  (void)n_in; (void)d_ws; (void)ws_size; (void)out_size;
  const float* x  = (const float*)d_in[0];
  const float* cw = (const float*)d_in[1];
  const float* cb = (const float*)d_in[2];
  const float* w1 = (const float*)d_in[3];
  const float* lw = (const float*)d_in[4];
  const float* lb = (const float*)d_in[5];
  float* out = (float*)d_out;
  const int nb = in_sizes[0] / 1024;   // 2048 samples, one wave each
  hipLaunchKernelGGL(qiddm_wave, dim3(nb), dim3(64), 0, stream,
                     x, cw, cb, w1, lw, lb, out);
}